// Round 6
// baseline (970.936 us; speedup 1.0000x reference)
//
#include <hip/hip_runtime.h>
#include <hip/hip_bf16.h>

// GATv2 x2 on MI355X. N=100000, E=3200000, D=128, H=1, C1=16, C2=32.
// Inputs f32; d_out f32, 3E floats = [edges(2E) | alpha2(E)].
// Round-12: nodeB1 pinned at 361-420us across FOUR structural variants; the
// invariant is the dependent random gather (rec -> xl1[src] -> acc). nodeB2
// (same rec stream, no gather) never shows in top-5 => gather chain is the
// bottleneck. Fix: PAYLOAD-CARRY -- edge1bin writes the 32B xl1[src] row
// next to each record; nodeB1p becomes a pure coalesced stream + LDS atomics
// (zero random accesses). Needs ~161MB ws -> 3-tier gate:
//   tier1 ws>=161MB: payload path (this round's experiment)
//   tier2 ws>= 32MB: exact round-4 path (proven 846us, no regression)
//   tier0: round-5/6 known-good fallback
//
// d_out layout (tier1/2 identical):
//  A [0,E):    e      score1 -> score2 (slot-in-place)
//  R [E,2E):   xl2/xr2 (N*64 bf16 = E floats) -> den2(N f32) at R base
//  C [2E,3E):  den1(N) xl1(8N) xr1(8N) out1(8N) = 2.5M floats
//  edges passthrough overwrites [0,2E) LAST.
// d_ws: dp uint2[782*5120] (32MB) | gcur (8KB) | pay uint4[782*5120*2] (128MB)

#define NN 100000
#define EE 3200000
#define DD 128
#define CC1 16
#define CC2 32
#define NEG_SLOPE 0.2f

#define NPB  128                        // nodes per bucket
#define NBK  782                        // ceil(NN/NPB); 782*128 = 100096
#define BCAP 5120                       // records/bucket (mean 4092, +16 sigma)
#define ACH  4096                       // edges per edge*bin block (16/thread)
#define ABLK 782                        // ceil(EE/ACH)

typedef __hip_bfloat16 bf16;

__device__ __forceinline__ float b2f(bf16 v) { return __bfloat162float(v); }

// load 8 consecutive bf16 -> 8 floats (one 16B load); bases verified 16B-aligned
__device__ __forceinline__ void ld8bf(const bf16* p, float* f) {
    uint4 u = *(const uint4*)p;
    const unsigned w[4] = {u.x, u.y, u.z, u.w};
#pragma unroll
    for (int i = 0; i < 4; i++) {
        f[2 * i]     = __uint_as_float(w[i] << 16);
        f[2 * i + 1] = __uint_as_float(w[i] & 0xffff0000u);
    }
}

// Order-preserving float<->uint encode for atomicMax (fallback path only).
__device__ __forceinline__ unsigned enc_f(float x) {
    unsigned b = __float_as_uint(x);
    return (b & 0x80000000u) ? ~b : (b | 0x80000000u);
}
__device__ __forceinline__ float dec_f(unsigned u) {
    unsigned b = (u & 0x80000000u) ? (u & 0x7fffffffu) : ~u;
    return __uint_as_float(b);
}

// ---------- Layer-1 node transform: xl1/xr1 = x@W + b (bf16 out) ----------
__global__ void lin1_kernel(const float* __restrict__ x,
                            const float* __restrict__ Wl, const float* __restrict__ bl,
                            const float* __restrict__ Wr, const float* __restrict__ br,
                            bf16* __restrict__ xl1, bf16* __restrict__ xr1) {
    __shared__ float Ws[DD][32];   // col<16: Wl, col>=16: Wr
    __shared__ float xs[8][DD];
    const int t = threadIdx.x;
    for (int i = t; i < DD * CC1; i += 256) {
        int k = i >> 4, c = i & 15;
        Ws[k][c]      = Wl[i];
        Ws[k][c + 16] = Wr[i];
    }
    const int node0 = blockIdx.x * 8;
    for (int i = t; i < 8 * DD; i += 256) {
        int n = i >> 7, k = i & 127;
        xs[n][k] = x[(node0 + n) * DD + k];
    }
    __syncthreads();
    const int n = t >> 5, c = t & 31;
    const int node = node0 + n;
    float acc = 0.f;
#pragma unroll 16
    for (int k = 0; k < DD; k++) acc += xs[n][k] * Ws[k][c];
    if (c < 16) xl1[node * CC1 + c]        = __float2bfloat16(acc + bl[c]);
    else        xr1[node * CC1 + (c - 16)] = __float2bfloat16(acc + br[c - 16]);
}

// ---------- FAST: Layer-1 edge scores fused with bucket binning ----------
// record = ( d&127 | src<<7 , e1 ); pay (tier1) = raw 32B xl1[src] row.
__global__ void edge1bin_kernel(const int* __restrict__ edges,
                                const float* __restrict__ ew,
                                const bf16* __restrict__ xl1, const bf16* __restrict__ xr1,
                                const float* __restrict__ We1, const float* __restrict__ att1,
                                float* __restrict__ e1,
                                uint2* __restrict__ tmp, int* __restrict__ gcur,
                                uint4* __restrict__ pay) {   // null on tier2
    __shared__ float Wes[CC1], atts[CC1];
    __shared__ int cnts[NBK], gbase[NBK], lfill[NBK];
    const int t = threadIdx.x;
    if (t < CC1) { Wes[t] = We1[t]; atts[t] = att1[t]; }
    for (int b = t; b < NBK; b += 256) { cnts[b] = 0; lfill[b] = 0; }
    __syncthreads();
    const int base = blockIdx.x * ACH;
    unsigned pk[16]; float ev[16]; int bk[16];
#pragma unroll
    for (int k = 0; k < 16; k++) {
        const int i = base + k * 256 + t;
        bk[k] = -1;
        if (i < EE) {
            const int s = edges[i], d = edges[EE + i];
            const float w = ew[i];
            float a[CC1], b[CC1];
            ld8bf(xl1 + s * CC1, a); ld8bf(xl1 + s * CC1 + 8, a + 8);
            ld8bf(xr1 + d * CC1, b); ld8bf(xr1 + d * CC1 + 8, b + 8);
            float acc = 0.f;
#pragma unroll
            for (int c = 0; c < CC1; c++) {
                float v = a[c] + b[c] + w * Wes[c];
                v = v > 0.f ? v : NEG_SLOPE * v;
                acc += v * atts[c];
            }
            e1[i] = acc;
            bk[k] = d >> 7;
            pk[k] = (unsigned)(d & 127) | ((unsigned)s << 7);
            ev[k] = acc;
            atomicAdd(&cnts[bk[k]], 1);
        }
    }
    __syncthreads();
    for (int b = t; b < NBK; b += 256)
        if (cnts[b] > 0) gbase[b] = atomicAdd(&gcur[b], cnts[b]);
    __syncthreads();
#pragma unroll
    for (int k = 0; k < 16; k++) {
        if (bk[k] >= 0) {
            const int slot = gbase[bk[k]] + atomicAdd(&lfill[bk[k]], 1);
            const size_t gs = (size_t)bk[k] * BCAP + slot;
            tmp[gs] = make_uint2(pk[k], __float_as_uint(ev[k]));
            if (pay) {                       // tier1: re-read row (L2-hot), store
                const int s = (int)(pk[k] >> 7);
                const uint4* xp = (const uint4*)(xl1 + s * CC1);
                pay[2 * gs]     = xp[0];
                pay[2 * gs + 1] = xp[1];
            }
        }
    }
}

// ---------- TIER1: per-bucket layer-1 softmax + aggregation, payload-carry ----
// Pure coalesced streams (dp 8B + pay 32B per record), ZERO random accesses.
__global__ void nodeB1p_kernel(const uint2* __restrict__ tmp, const int* __restrict__ gcur,
                               const uint4* __restrict__ pay,
                               float* __restrict__ den1, bf16* __restrict__ out1) {
    __shared__ float den[NPB];
    __shared__ float acc[NPB][CC1 + 1];   // +1 pad: kill 16-bank stride conflict
    const int t = threadIdx.x;            // 512
    const int b = blockIdx.x;
    const int count = gcur[b];
    const uint2* rec = tmp + (size_t)b * BCAP;
    const uint4* pp  = pay + (size_t)b * BCAP * 2;
    for (int i = t; i < NPB; i += 512) den[i] = 0.f;
    for (int i = t; i < NPB * (CC1 + 1); i += 512) ((float*)acc)[i] = 0.f;
    __syncthreads();
    for (int j = t; j < count; j += 512) {
        const uint2 r  = rec[j];          // coalesced
        const uint4 A0 = pp[2 * j];       // coalesced 32B/lane
        const uint4 A1 = pp[2 * j + 1];
        const float p = __expf(__uint_as_float(r.y));
        const int d = (int)(r.x & 127u);
        const unsigned wds[8] = {A0.x, A0.y, A0.z, A0.w, A1.x, A1.y, A1.z, A1.w};
#pragma unroll
        for (int w = 0; w < 8; w++) {
            atomicAdd(&acc[d][2 * w],     p * __uint_as_float(wds[w] << 16));
            atomicAdd(&acc[d][2 * w + 1], p * __uint_as_float(wds[w] & 0xffff0000u));
        }
        atomicAdd(&den[d], p);
    }
    __syncthreads();
    const int n0 = b * NPB;
    for (int i = t; i < NPB * CC1; i += 512) {
        const int d = i >> 4, cc = i & 15;
        const int node = n0 + d;
        if (node < NN) {
            const float l = den[d];
            out1[node * CC1 + cc] = __float2bfloat16(l > 0.f ? acc[d][cc] / l : 0.f);
            if (cc == 0) den1[node] = l;
        }
    }
}

// ---------- TIER2: round-4 gather version (proven 846us path) ----------
__global__ void nodeB1g_kernel(const uint2* __restrict__ tmp, const int* __restrict__ gcur,
                               const bf16* __restrict__ xl1,
                               float* __restrict__ den1, bf16* __restrict__ out1) {
    __shared__ float den[NPB];
    __shared__ float acc[NPB][CC1 + 1];
    const int t = threadIdx.x;            // 512
    const int b = blockIdx.x;
    const int count = gcur[b];
    const uint2* rec = tmp + (size_t)b * BCAP;
    for (int i = t; i < NPB; i += 512) den[i] = 0.f;
    for (int i = t; i < NPB * (CC1 + 1); i += 512) ((float*)acc)[i] = 0.f;
    __syncthreads();
    const int g = t >> 4, c = t & 15;
    int j0 = g * 4;
    for (; j0 + 4 <= count; j0 += 128) {
        const uint2 r0 = rec[j0 + 0];
        const uint2 r1 = rec[j0 + 1];
        const uint2 r2 = rec[j0 + 2];
        const uint2 r3 = rec[j0 + 3];
        const float x0 = b2f(xl1[(r0.x >> 7) * CC1 + c]);
        const float x1 = b2f(xl1[(r1.x >> 7) * CC1 + c]);
        const float x2 = b2f(xl1[(r2.x >> 7) * CC1 + c]);
        const float x3 = b2f(xl1[(r3.x >> 7) * CC1 + c]);
        const float p0 = __expf(__uint_as_float(r0.y));
        const float p1 = __expf(__uint_as_float(r1.y));
        const float p2 = __expf(__uint_as_float(r2.y));
        const float p3 = __expf(__uint_as_float(r3.y));
        atomicAdd(&acc[r0.x & 127u][c], p0 * x0);
        atomicAdd(&acc[r1.x & 127u][c], p1 * x1);
        atomicAdd(&acc[r2.x & 127u][c], p2 * x2);
        atomicAdd(&acc[r3.x & 127u][c], p3 * x3);
        if (c == 0) {
            atomicAdd(&den[r0.x & 127u], p0);
            atomicAdd(&den[r1.x & 127u], p1);
            atomicAdd(&den[r2.x & 127u], p2);
            atomicAdd(&den[r3.x & 127u], p3);
        }
    }
    for (int j = j0; j < min(j0 + 4, count); j++) {
        const uint2 r = rec[j];
        const float p = __expf(__uint_as_float(r.y));
        atomicAdd(&acc[r.x & 127u][c], p * b2f(xl1[(r.x >> 7) * CC1 + c]));
        if (c == 0) atomicAdd(&den[r.x & 127u], p);
    }
    __syncthreads();
    const int n0 = b * NPB;
    for (int i = t; i < NPB * CC1; i += 512) {
        const int d = i >> 4, cc = i & 15;
        const int node = n0 + d;
        if (node < NN) {
            const float l = den[d];
            out1[node * CC1 + cc] = __float2bfloat16(l > 0.f ? acc[d][cc] / l : 0.f);
            if (cc == 0) den1[node] = l;
        }
    }
}

// ---------- Layer-2 node transform: h = relu(out1+b1); xl2/xr2 = h@W2 (bf16) ----------
__global__ void lin2_kernel(const bf16* __restrict__ out1, const float* __restrict__ b1,
                            const float* __restrict__ Wl2, const float* __restrict__ bl2,
                            const float* __restrict__ Wr2, const float* __restrict__ br2,
                            bf16* __restrict__ xl2, bf16* __restrict__ xr2) {
    __shared__ float Ws[CC1][64];  // col<32: Wl2, col>=32: Wr2
    __shared__ float hs[4][CC1];
    const int t = threadIdx.x;
    for (int i = t; i < CC1 * CC2; i += 256) {
        int k = i >> 5, c = i & 31;
        Ws[k][c]      = Wl2[i];
        Ws[k][c + 32] = Wr2[i];
    }
    const int node0 = blockIdx.x * 4;
    if (t < 64) {
        int n = t >> 4, k = t & 15;
        float v = b2f(out1[(node0 + n) * CC1 + k]) + b1[k];
        hs[n][k] = v > 0.f ? v : 0.f;
    }
    __syncthreads();
    const int n = t >> 6, c = t & 63;
    const int node = node0 + n;
    float acc = 0.f;
#pragma unroll
    for (int k = 0; k < CC1; k++) acc += hs[n][k] * Ws[k][c];
    if (c < 32) xl2[node * CC2 + c]        = __float2bfloat16(acc + bl2[c]);
    else        xr2[node * CC2 + (c - 32)] = __float2bfloat16(acc + br2[c - 32]);
}

// ---------- FAST: Layer-2 edge scores fused with bucket binning ----------
// alpha1 = exp(e1)/den1 inline (no max shift); record = ( d&127 , e2 ).
__global__ void edge2bin_kernel(const int* __restrict__ edges,
                                float* __restrict__ e,     // in: score1, out: score2
                                const float* __restrict__ den1,
                                const bf16* __restrict__ xl2, const bf16* __restrict__ xr2,
                                const float* __restrict__ We2, const float* __restrict__ att2,
                                uint2* __restrict__ tmp, int* __restrict__ gcur) {
    __shared__ float Wes[CC2], atts[CC2];
    __shared__ int cnts[NBK], gbase[NBK], lfill[NBK];
    const int t = threadIdx.x;
    if (t < CC2) { Wes[t] = We2[t]; atts[t] = att2[t]; }
    for (int b = t; b < NBK; b += 256) { cnts[b] = 0; lfill[b] = 0; }
    __syncthreads();
    const int base = blockIdx.x * ACH;
    unsigned pk[16]; float ev[16]; int bk[16];
#pragma unroll
    for (int k = 0; k < 16; k++) {
        const int i = base + k * 256 + t;
        bk[k] = -1;
        if (i < EE) {
            const int s = edges[i], d = edges[EE + i];
            const float w = __expf(e[i]) / (den1[d] + 1e-16f);  // alpha1, no shift
            float a[CC2], b[CC2];
#pragma unroll
            for (int q = 0; q < 4; q++) {
                ld8bf(xl2 + s * CC2 + 8 * q, a + 8 * q);
                ld8bf(xr2 + d * CC2 + 8 * q, b + 8 * q);
            }
            float acc = 0.f;
#pragma unroll
            for (int c = 0; c < CC2; c++) {
                float v = a[c] + b[c] + w * Wes[c];
                v = v > 0.f ? v : NEG_SLOPE * v;
                acc += v * atts[c];
            }
            e[i] = acc;
            bk[k] = d >> 7;
            pk[k] = (unsigned)(d & 127);
            ev[k] = acc;
            atomicAdd(&cnts[bk[k]], 1);
        }
    }
    __syncthreads();
    for (int b = t; b < NBK; b += 256)
        if (cnts[b] > 0) gbase[b] = atomicAdd(&gcur[b], cnts[b]);
    __syncthreads();
#pragma unroll
    for (int k = 0; k < 16; k++) {
        if (bk[k] >= 0) {
            const int slot = gbase[bk[k]] + atomicAdd(&lfill[bk[k]], 1);
            tmp[(size_t)bk[k] * BCAP + slot] = make_uint2(pk[k], __float_as_uint(ev[k]));
        }
    }
}

// ---------- FAST: per-bucket layer-2 denominator, SINGLE pass, 4x batch ----------
__global__ void nodeB2_kernel(const uint2* __restrict__ tmp, const int* __restrict__ gcur,
                              float* __restrict__ den2) {
    __shared__ float den[NPB];
    const int t = threadIdx.x;            // 512
    const int b = blockIdx.x;
    const int count = gcur[b];
    const uint2* rec = tmp + (size_t)b * BCAP;
    for (int i = t; i < NPB; i += 512) den[i] = 0.f;
    __syncthreads();
    int j0 = t * 4;
    for (; j0 + 4 <= count; j0 += 2048) {
        const uint2 r0 = rec[j0 + 0];
        const uint2 r1 = rec[j0 + 1];
        const uint2 r2 = rec[j0 + 2];
        const uint2 r3 = rec[j0 + 3];
        atomicAdd(&den[r0.x & 127u], __expf(__uint_as_float(r0.y)));
        atomicAdd(&den[r1.x & 127u], __expf(__uint_as_float(r1.y)));
        atomicAdd(&den[r2.x & 127u], __expf(__uint_as_float(r2.y)));
        atomicAdd(&den[r3.x & 127u], __expf(__uint_as_float(r3.y)));
    }
    for (int j = j0; j < min(j0 + 4, count); j++) {
        const uint2 r = rec[j];
        atomicAdd(&den[r.x & 127u], __expf(__uint_as_float(r.y)));
    }
    __syncthreads();
    const int n0 = b * NPB;
    for (int i = t; i < NPB; i += 512) {
        const int node = n0 + i;
        if (node < NN) den2[node] = den[i];
    }
}

// ---------- FAST: alpha2 = exp(e2)/den2[dst] -> [2E,3E) ----------
__global__ void final2_kernel(const int* __restrict__ dst,
                              const float* __restrict__ e,
                              const float* __restrict__ den2,
                              float* __restrict__ out) {
    const int i = blockIdx.x * 256 + threadIdx.x;
    const int d = dst[i];
    out[2 * EE + i] = __expf(e[i]) / (den2[d] + 1e-16f);
}

// ---------- edges passthrough -> floats [0,2E), LAST ----------
__global__ void edges_kernel(const int* __restrict__ edges, float* __restrict__ out) {
    const int i = blockIdx.x * 256 + threadIdx.x;   // grid covers 2E
    out[i] = (float)edges[i];
}

// ================= FALLBACK PATH (round-5/6, known-good) =================
__global__ void edge1f_kernel(const int* __restrict__ edges,
                              const float* __restrict__ ew,
                              const bf16* __restrict__ xl1, const bf16* __restrict__ xr1,
                              const float* __restrict__ We1, const float* __restrict__ att1,
                              float* __restrict__ e1, int* __restrict__ cnt,
                              unsigned* __restrict__ m1enc) {
    __shared__ float Wes[CC1], atts[CC1];
    if (threadIdx.x < CC1) {
        Wes[threadIdx.x]  = We1[threadIdx.x];
        atts[threadIdx.x] = att1[threadIdx.x];
    }
    __syncthreads();
    const int e = blockIdx.x * 256 + threadIdx.x;
    const int s = edges[e], d = edges[EE + e];
    const float w = ew[e];
    float a[CC1], b[CC1];
    ld8bf(xl1 + s * CC1, a); ld8bf(xl1 + s * CC1 + 8, a + 8);
    ld8bf(xr1 + d * CC1, b); ld8bf(xr1 + d * CC1 + 8, b + 8);
    float acc = 0.f;
#pragma unroll
    for (int c = 0; c < CC1; c++) {
        float v = a[c] + b[c] + w * Wes[c];
        v = v > 0.f ? v : NEG_SLOPE * v;
        acc += v * atts[c];
    }
    e1[e] = acc;
    atomicAdd(&cnt[d], 1);
    atomicMax(&m1enc[d], enc_f(acc));
}

__global__ void scan_kernel(const int* __restrict__ cnt, int* __restrict__ off) {
    __shared__ int part[1024];
    const int t = threadIdx.x;
    const int chunk = (NN + 1023) / 1024;
    const int beg = t * chunk;
    const int end = min(beg + chunk, NN);
    int s = 0;
    for (int i = beg; i < end; i++) s += cnt[i];
    part[t] = s;
    __syncthreads();
    for (int o = 1; o < 1024; o <<= 1) {
        int v = (t >= o) ? part[t - o] : 0;
        __syncthreads();
        part[t] += v;
        __syncthreads();
    }
    int run = (t > 0) ? part[t - 1] : 0;
    for (int i = beg; i < end; i++) { off[i] = run; run += cnt[i]; }
    if (t == 1023) off[NN] = part[1023];
}

__global__ void scatter_kernel(const int* __restrict__ edges,
                               const int* __restrict__ off, int* __restrict__ cnt,
                               int* __restrict__ csr) {
    const int i = blockIdx.x * 256 + threadIdx.x;
    const int d = edges[EE + i];
    const int r = atomicSub(&cnt[d], 1);
    csr[off[d] + r - 1] = i;
}

__global__ void node1s_kernel(const int* __restrict__ off, const int* __restrict__ csr,
                              const int* __restrict__ edges,
                              const float* __restrict__ e1, const bf16* __restrict__ xl1,
                              float* __restrict__ den1, bf16* __restrict__ out1) {
    const int t = blockIdx.x * 256 + threadIdx.x;
    const int n = t >> 4, c = t & 15;
    const int beg = off[n], end = off[n + 1];
    float m = -3.0e38f, l = 0.f, acc = 0.f;
    for (int j = beg; j < end; j++) {
        const int eid = csr[j];
        const float s = e1[eid];
        const int src = edges[eid];
        const float xv = b2f(xl1[src * CC1 + c]);
        if (s > m) { const float r = __expf(m - s); l *= r; acc *= r; m = s; }
        const float p = __expf(s - m);
        l += p; acc += p * xv;
    }
    out1[n * CC1 + c] = __float2bfloat16(l > 0.f ? acc / l : 0.f);
    if (c == 0) den1[n] = l;
}

__global__ void edge2enc_kernel(const int* __restrict__ edges,
                                float* __restrict__ e,
                                const unsigned* __restrict__ m1enc,
                                const float* __restrict__ den1,
                                const bf16* __restrict__ xl2, const bf16* __restrict__ xr2,
                                const float* __restrict__ We2, const float* __restrict__ att2) {
    __shared__ float Wes[CC2], atts[CC2];
    if (threadIdx.x < CC2) {
        Wes[threadIdx.x]  = We2[threadIdx.x];
        atts[threadIdx.x] = att2[threadIdx.x];
    }
    __syncthreads();
    const int i = blockIdx.x * 256 + threadIdx.x;
    const int s = edges[i], d = edges[EE + i];
    const float w = __expf(e[i] - dec_f(m1enc[d])) / (den1[d] + 1e-16f);
    float a[CC2], b[CC2];
#pragma unroll
    for (int q = 0; q < 4; q++) {
        ld8bf(xl2 + s * CC2 + 8 * q, a + 8 * q);
        ld8bf(xr2 + d * CC2 + 8 * q, b + 8 * q);
    }
    float acc = 0.f;
#pragma unroll
    for (int c = 0; c < CC2; c++) {
        float v = a[c] + b[c] + w * Wes[c];
        v = v > 0.f ? v : NEG_SLOPE * v;
        acc += v * atts[c];
    }
    e[i] = acc;
}

__global__ void max2_kernel(const int* __restrict__ dst, const float* __restrict__ e2,
                            unsigned* __restrict__ m2) {
    const int i = blockIdx.x * 256 + threadIdx.x;
    atomicMax(&m2[dst[i]], enc_f(e2[i]));
}

__global__ void num2_kernel(const int* __restrict__ dst,
                            const unsigned* __restrict__ m2,
                            float* __restrict__ e, float* __restrict__ den2) {
    const int i = blockIdx.x * 256 + threadIdx.x;
    const int d = dst[i];
    const float v = __expf(e[i] - dec_f(m2[d]));
    e[i] = v;
    atomicAdd(&den2[d], v);
}

__global__ void finalold_kernel(const int* __restrict__ dst,
                                const float* __restrict__ e,
                                const float* __restrict__ den2,
                                float* __restrict__ out) {
    const int i = blockIdx.x * 256 + threadIdx.x;
    const int d = dst[i];
    out[2 * EE + i] = e[i] / (den2[d] + 1e-16f);
}

extern "C" void kernel_launch(void* const* d_in, const int* in_sizes, int n_in,
                              void* d_out, int out_size, void* d_ws, size_t ws_size,
                              hipStream_t stream) {
    const float* x    = (const float*)d_in[0];
    const int*  edges = (const int*)d_in[1];
    const float* ew   = (const float*)d_in[2];
    const float* Wl1  = (const float*)d_in[3];
    const float* bl1  = (const float*)d_in[4];
    const float* Wr1  = (const float*)d_in[5];
    const float* br1  = (const float*)d_in[6];
    const float* We1  = (const float*)d_in[7];
    const float* att1 = (const float*)d_in[8];
    const float* b1   = (const float*)d_in[9];
    const float* Wl2  = (const float*)d_in[10];
    const float* bl2  = (const float*)d_in[11];
    const float* Wr2  = (const float*)d_in[12];
    const float* br2  = (const float*)d_in[13];
    const float* We2  = (const float*)d_in[14];
    const float* att2 = (const float*)d_in[15];
    float* out = (float*)d_out;

    const int* dst = edges + EE;
    const int EG = EE / 256;                          // 12500

    // ---- Workspace: dp (32MB) | gcur (8KB) | pay (128MB, tier1 only) ----
    const size_t dpBytes = (size_t)NBK * BCAP * 8;
    uint2* tmp  = (uint2*)d_ws;
    int*   gcur = (int*)((char*)d_ws + dpBytes);
    uint4* pay  = (uint4*)((char*)d_ws + dpBytes + 8192);
    const size_t ws_t2 = dpBytes + 8192;                               // 32MB
    const size_t ws_t1 = dpBytes + 8192 + (size_t)NBK * BCAP * 32;     // 160MB
    const int tier = (d_ws && ws_size >= ws_t1) ? 1
                   : (d_ws && ws_size >= ws_t2) ? 2 : 0;

    if (tier >= 1 || tier == 2) { /* fallthrough structure below */ }

    if (tier != 0) {
        // ---- fast layout ----
        float* e = out;                               // [0,E)
        bf16*  xl2  = (bf16*)(out + EE);              // R: N*32 bf16
        bf16*  xr2  = xl2 + NN * CC2;                 // R: N*32 bf16
        float* den2 = out + EE;                       // R base (xl2/xr2 dead)
        float* den1 = out + 2 * EE;                   // C region
        bf16*  xl1  = (bf16*)(den1 + NN);             // 16B-aligned
        bf16*  xr1  = xl1 + NN * CC1;
        bf16*  out1 = xr1 + NN * CC1;

        hipMemsetAsync(gcur, 0, (size_t)NBK * sizeof(int), stream);
        lin1_kernel    <<<NN / 8, 256, 0, stream>>>(x, Wl1, bl1, Wr1, br1, xl1, xr1);
        edge1bin_kernel<<<ABLK, 256, 0, stream>>>(edges, ew, xl1, xr1, We1, att1,
                                                  e, tmp, gcur,
                                                  tier == 1 ? pay : nullptr);
        if (tier == 1)
            nodeB1p_kernel<<<NBK, 512, 0, stream>>>(tmp, gcur, pay, den1, out1);
        else
            nodeB1g_kernel<<<NBK, 512, 0, stream>>>(tmp, gcur, xl1, den1, out1);
        lin2_kernel    <<<NN / 4, 256, 0, stream>>>(out1, b1, Wl2, bl2, Wr2, br2, xl2, xr2);
        hipMemsetAsync(gcur, 0, (size_t)NBK * sizeof(int), stream);
        edge2bin_kernel<<<ABLK, 256, 0, stream>>>(edges, e, den1, xl2, xr2,
                                                  We2, att2, tmp, gcur);
        // xl2/xr2 dead: den2 overlays R base
        nodeB2_kernel  <<<NBK, 512, 0, stream>>>(tmp, gcur, den2);
        final2_kernel  <<<EG, 256, 0, stream>>>(dst, e, den2, out);
        edges_kernel   <<<2 * EG, 256, 0, stream>>>(edges, out);
    } else {
        // ---- fallback layout (round-6) ----
        float*    e    = out;
        int*      csr  = (int*)(out + EE);
        bf16*     xl2  = (bf16*)(out + EE);
        bf16*     xr2  = xl2 + NN * CC2;
        unsigned* m2   = (unsigned*)(out + EE);
        float*    den2 = (float*)(out + EE) + NN;
        int*      off   = (int*)(out + 2 * EE);
        unsigned* m1enc = (unsigned*)(off + NN + 4);
        int*      cnt   = (int*)(m1enc + NN);
        float*    den1  = (float*)(cnt + NN);
        bf16*     xl1   = (bf16*)(den1 + NN);
        bf16*     xr1   = xl1 + NN * CC1;
        bf16*     out1  = xr1 + NN * CC1;

        hipMemsetAsync(m1enc, 0, (size_t)2 * NN * sizeof(int), stream);  // m1enc+cnt
        lin1_kernel   <<<NN / 8, 256, 0, stream>>>(x, Wl1, bl1, Wr1, br1, xl1, xr1);
        edge1f_kernel <<<EG, 256, 0, stream>>>(edges, ew, xl1, xr1, We1, att1,
                                               e, cnt, m1enc);
        scan_kernel   <<<1, 1024, 0, stream>>>(cnt, off);
        scatter_kernel<<<EG, 256, 0, stream>>>(edges, off, cnt, csr);
        node1s_kernel <<<NN * 16 / 256, 256, 0, stream>>>(off, csr, edges, e, xl1,
                                                          den1, out1);
        lin2_kernel   <<<NN / 4, 256, 0, stream>>>(out1, b1, Wl2, bl2, Wr2, br2, xl2, xr2);
        edge2enc_kernel<<<EG, 256, 0, stream>>>(edges, e, m1enc, den1, xl2, xr2,
                                                We2, att2);
        hipMemsetAsync(m2, 0, (size_t)2 * NN * sizeof(float), stream);
        max2_kernel   <<<EG, 256, 0, stream>>>(dst, e, m2);
        num2_kernel   <<<EG, 256, 0, stream>>>(dst, m2, e, den2);
        finalold_kernel<<<EG, 256, 0, stream>>>(dst, e, den2, out);
        edges_kernel  <<<2 * EG, 256, 0, stream>>>(edges, out);
    }
}

// Round 7
// 596.011 us; speedup vs baseline: 1.6291x; 1.6291x over previous
//
#include <hip/hip_runtime.h>
#include <hip/hip_bf16.h>

// GATv2 x2 on MI355X. N=100000, E=3200000, D=128, H=1, C1=16, C2=32.
// Inputs f32; d_out f32, 3E floats = [edges(2E) | alpha2(E)].
// Round-13: mechanism of the 360us nodeB1 plateau identified. Five variants
// (incl. a ZERO-random-access payload stream) all ran 359-420us; invariant =
// 16-17 LDS lane-atomics per record. 54.4M lane-atomics / 256 CU / 861K cyc
// => ~4 cyc per LDS atomic lane-op (the un-counted LDS RMW pipe). nodeB2
// (1 atomic/rec, same stream) is ~21us -- confirms the model.
// Fix: REGISTER accumulation via pair-CSR:
//   edge1bin (unchanged)  -> bucket records (d,src,e), no global atomics
//   scanB                 -> bucket bases from gcur; off[NN]=E
//   binB2 (per bucket)    -> LDS hist+scan+countdown (2 atomics/rec),
//                            writes csr2[pos]=(src, p=exp(e)) in 33KB window
//                            and off[node] wholesale
//   node1f (per node x16) -> stream pairs, register FMA, zero LDS atomics
//                            (R0-proven shape)
//
// d_out layout:
//  A [0,E):    e      score1 -> score2 (slot-in-place)
//  R [E,2E):   xl2/xr2 (N*64 bf16 = E floats) -> den2(N f32) at R base
//  C [2E,3E):  den1(N) xl1(8N) xr1(8N) out1(8N) = 2.5M floats
//  edges passthrough overwrites [0,2E) LAST.
// d_ws (~58MB; round-6 proved ws>=160MB): tmp uint2[782*5120] (32MB) |
//   gcur[782] | bbase[782] | csr2 uint2[E] (25.6MB) | off[NN+4]

#define NN 100000
#define EE 3200000
#define DD 128
#define CC1 16
#define CC2 32
#define NEG_SLOPE 0.2f

#define NPB  128                        // nodes per bucket
#define NBK  782                        // ceil(NN/NPB); 782*128 = 100096
#define BCAP 5120                       // records/bucket (mean 4092, +16 sigma)
#define ACH  4096                       // edges per edge*bin block (16/thread)
#define ABLK 782                        // ceil(EE/ACH)

typedef __hip_bfloat16 bf16;

__device__ __forceinline__ float b2f(bf16 v) { return __bfloat162float(v); }

// load 8 consecutive bf16 -> 8 floats (one 16B load); bases verified 16B-aligned
__device__ __forceinline__ void ld8bf(const bf16* p, float* f) {
    uint4 u = *(const uint4*)p;
    const unsigned w[4] = {u.x, u.y, u.z, u.w};
#pragma unroll
    for (int i = 0; i < 4; i++) {
        f[2 * i]     = __uint_as_float(w[i] << 16);
        f[2 * i + 1] = __uint_as_float(w[i] & 0xffff0000u);
    }
}

// Order-preserving float<->uint encode for atomicMax (fallback path only).
__device__ __forceinline__ unsigned enc_f(float x) {
    unsigned b = __float_as_uint(x);
    return (b & 0x80000000u) ? ~b : (b | 0x80000000u);
}
__device__ __forceinline__ float dec_f(unsigned u) {
    unsigned b = (u & 0x80000000u) ? (u & 0x7fffffffu) : ~u;
    return __uint_as_float(b);
}

// ---------- Layer-1 node transform: xl1/xr1 = x@W + b (bf16 out) ----------
__global__ void lin1_kernel(const float* __restrict__ x,
                            const float* __restrict__ Wl, const float* __restrict__ bl,
                            const float* __restrict__ Wr, const float* __restrict__ br,
                            bf16* __restrict__ xl1, bf16* __restrict__ xr1) {
    __shared__ float Ws[DD][32];   // col<16: Wl, col>=16: Wr
    __shared__ float xs[8][DD];
    const int t = threadIdx.x;
    for (int i = t; i < DD * CC1; i += 256) {
        int k = i >> 4, c = i & 15;
        Ws[k][c]      = Wl[i];
        Ws[k][c + 16] = Wr[i];
    }
    const int node0 = blockIdx.x * 8;
    for (int i = t; i < 8 * DD; i += 256) {
        int n = i >> 7, k = i & 127;
        xs[n][k] = x[(node0 + n) * DD + k];
    }
    __syncthreads();
    const int n = t >> 5, c = t & 31;
    const int node = node0 + n;
    float acc = 0.f;
#pragma unroll 16
    for (int k = 0; k < DD; k++) acc += xs[n][k] * Ws[k][c];
    if (c < 16) xl1[node * CC1 + c]        = __float2bfloat16(acc + bl[c]);
    else        xr1[node * CC1 + (c - 16)] = __float2bfloat16(acc + br[c - 16]);
}

// ---------- FAST: Layer-1 edge scores fused with bucket binning ----------
// record = ( d&127 | src<<7 , e1 ); NO random global atomics.
__global__ void edge1bin_kernel(const int* __restrict__ edges,
                                const float* __restrict__ ew,
                                const bf16* __restrict__ xl1, const bf16* __restrict__ xr1,
                                const float* __restrict__ We1, const float* __restrict__ att1,
                                float* __restrict__ e1,
                                uint2* __restrict__ tmp, int* __restrict__ gcur) {
    __shared__ float Wes[CC1], atts[CC1];
    __shared__ int cnts[NBK], gbase[NBK], lfill[NBK];
    const int t = threadIdx.x;
    if (t < CC1) { Wes[t] = We1[t]; atts[t] = att1[t]; }
    for (int b = t; b < NBK; b += 256) { cnts[b] = 0; lfill[b] = 0; }
    __syncthreads();
    const int base = blockIdx.x * ACH;
    unsigned pk[16]; float ev[16]; int bk[16];
#pragma unroll
    for (int k = 0; k < 16; k++) {
        const int i = base + k * 256 + t;
        bk[k] = -1;
        if (i < EE) {
            const int s = edges[i], d = edges[EE + i];
            const float w = ew[i];
            float a[CC1], b[CC1];
            ld8bf(xl1 + s * CC1, a); ld8bf(xl1 + s * CC1 + 8, a + 8);
            ld8bf(xr1 + d * CC1, b); ld8bf(xr1 + d * CC1 + 8, b + 8);
            float acc = 0.f;
#pragma unroll
            for (int c = 0; c < CC1; c++) {
                float v = a[c] + b[c] + w * Wes[c];
                v = v > 0.f ? v : NEG_SLOPE * v;
                acc += v * atts[c];
            }
            e1[i] = acc;
            bk[k] = d >> 7;
            pk[k] = (unsigned)(d & 127) | ((unsigned)s << 7);
            ev[k] = acc;
            atomicAdd(&cnts[bk[k]], 1);
        }
    }
    __syncthreads();
    for (int b = t; b < NBK; b += 256)
        if (cnts[b] > 0) gbase[b] = atomicAdd(&gcur[b], cnts[b]);
    __syncthreads();
#pragma unroll
    for (int k = 0; k < 16; k++) {
        if (bk[k] >= 0) {
            const int slot = gbase[bk[k]] + atomicAdd(&lfill[bk[k]], 1);
            tmp[(size_t)bk[k] * BCAP + slot] = make_uint2(pk[k], __float_as_uint(ev[k]));
        }
    }
}

// ---------- FAST: exclusive scan of gcur -> bbase; off[NN] = EE ----------
__global__ void scanB_kernel(const int* __restrict__ gcur, int* __restrict__ bbase,
                             int* __restrict__ off) {
    __shared__ int part[1024];
    const int t = threadIdx.x;
    part[t] = (t < NBK) ? gcur[t] : 0;
    __syncthreads();
    for (int o = 1; o < 1024; o <<= 1) {
        int v = (t >= o) ? part[t - o] : 0;
        __syncthreads();
        part[t] += v;
        __syncthreads();
    }
    if (t < NBK) bbase[t] = part[t] - gcur[t];   // exclusive prefix
    if (t == 0) off[NN] = EE;
}

// ---------- FAST: per-bucket CSR build: csr2[pos]=(src, p=exp(e)) ----------
// 2 LDS atomics/record (hist + countdown); random writes stay in 33KB window.
__global__ void binB2_kernel(const uint2* __restrict__ tmp, const int* __restrict__ gcur,
                             const int* __restrict__ bbase,
                             uint2* __restrict__ csr2, int* __restrict__ off) {
    __shared__ int cnt[NPB];     // histogram, then countdown cursor
    __shared__ int loff[NPB];    // local exclusive prefix
    const int t = threadIdx.x;   // 512
    const int b = blockIdx.x;
    const int count = gcur[b];
    const uint2* rec = tmp + (size_t)b * BCAP;
    for (int i = t; i < NPB; i += 512) cnt[i] = 0;
    __syncthreads();
    for (int j = t; j < count; j += 512) atomicAdd(&cnt[rec[j].x & 127u], 1);
    __syncthreads();
    if (t == 0) {                            // 128-value serial scan: trivial
        int run = 0;
#pragma unroll
        for (int i = 0; i < NPB; i++) { loff[i] = run; run += cnt[i]; }
    }
    __syncthreads();
    const int base = bbase[b];
    const int n0 = b * NPB;
    for (int i = t; i < NPB; i += 512) {     // off[] wholesale
        const int node = n0 + i;
        if (node < NN) off[node] = base + loff[i];
    }
    for (int j = t; j < count; j += 512) {
        const uint2 r = rec[j];
        const int d = (int)(r.x & 127u);
        const int rr = atomicSub(&cnt[d], 1);          // rr in [1..deg]
        const int pos = base + loff[d] + rr - 1;
        const float p = __expf(__uint_as_float(r.y));
        csr2[pos] = make_uint2(r.x >> 7, __float_as_uint(p));
    }
}

// ---------- FAST: per-node aggregation, REGISTER accumulation (R0 shape) ----
__global__ void node1f_kernel(const int* __restrict__ off, const uint2* __restrict__ csr2,
                              const bf16* __restrict__ xl1,
                              float* __restrict__ den1, bf16* __restrict__ out1) {
    const int t = blockIdx.x * 256 + threadIdx.x;   // grid covers N*16 exactly
    const int n = t >> 4, c = t & 15;
    const int beg = off[n], end = off[n + 1];
    float l = 0.f, acc = 0.f;
    for (int j = beg; j < end; j++) {
        const uint2 r = csr2[j];              // broadcast across 16 lanes
        const float p = __uint_as_float(r.y);
        acc += p * b2f(xl1[r.x * CC1 + c]);   // 32B/record group gather
        l += p;
    }
    out1[n * CC1 + c] = __float2bfloat16(l > 0.f ? acc / l : 0.f);
    if (c == 0) den1[n] = l;
}

// ---------- Layer-2 node transform: h = relu(out1+b1); xl2/xr2 = h@W2 (bf16) ----------
__global__ void lin2_kernel(const bf16* __restrict__ out1, const float* __restrict__ b1,
                            const float* __restrict__ Wl2, const float* __restrict__ bl2,
                            const float* __restrict__ Wr2, const float* __restrict__ br2,
                            bf16* __restrict__ xl2, bf16* __restrict__ xr2) {
    __shared__ float Ws[CC1][64];  // col<32: Wl2, col>=32: Wr2
    __shared__ float hs[4][CC1];
    const int t = threadIdx.x;
    for (int i = t; i < CC1 * CC2; i += 256) {
        int k = i >> 5, c = i & 31;
        Ws[k][c]      = Wl2[i];
        Ws[k][c + 32] = Wr2[i];
    }
    const int node0 = blockIdx.x * 4;
    if (t < 64) {
        int n = t >> 4, k = t & 15;
        float v = b2f(out1[(node0 + n) * CC1 + k]) + b1[k];
        hs[n][k] = v > 0.f ? v : 0.f;
    }
    __syncthreads();
    const int n = t >> 6, c = t & 63;
    const int node = node0 + n;
    float acc = 0.f;
#pragma unroll
    for (int k = 0; k < CC1; k++) acc += hs[n][k] * Ws[k][c];
    if (c < 32) xl2[node * CC2 + c]        = __float2bfloat16(acc + bl2[c]);
    else        xr2[node * CC2 + (c - 32)] = __float2bfloat16(acc + br2[c - 32]);
}

// ---------- FAST: Layer-2 edge scores fused with bucket binning ----------
// alpha1 = exp(e1)/den1 inline (no max shift); record = ( d&127 , e2 ).
__global__ void edge2bin_kernel(const int* __restrict__ edges,
                                float* __restrict__ e,     // in: score1, out: score2
                                const float* __restrict__ den1,
                                const bf16* __restrict__ xl2, const bf16* __restrict__ xr2,
                                const float* __restrict__ We2, const float* __restrict__ att2,
                                uint2* __restrict__ tmp, int* __restrict__ gcur) {
    __shared__ float Wes[CC2], atts[CC2];
    __shared__ int cnts[NBK], gbase[NBK], lfill[NBK];
    const int t = threadIdx.x;
    if (t < CC2) { Wes[t] = We2[t]; atts[t] = att2[t]; }
    for (int b = t; b < NBK; b += 256) { cnts[b] = 0; lfill[b] = 0; }
    __syncthreads();
    const int base = blockIdx.x * ACH;
    unsigned pk[16]; float ev[16]; int bk[16];
#pragma unroll
    for (int k = 0; k < 16; k++) {
        const int i = base + k * 256 + t;
        bk[k] = -1;
        if (i < EE) {
            const int s = edges[i], d = edges[EE + i];
            const float w = __expf(e[i]) / (den1[d] + 1e-16f);  // alpha1, no shift
            float a[CC2], b[CC2];
#pragma unroll
            for (int q = 0; q < 4; q++) {
                ld8bf(xl2 + s * CC2 + 8 * q, a + 8 * q);
                ld8bf(xr2 + d * CC2 + 8 * q, b + 8 * q);
            }
            float acc = 0.f;
#pragma unroll
            for (int c = 0; c < CC2; c++) {
                float v = a[c] + b[c] + w * Wes[c];
                v = v > 0.f ? v : NEG_SLOPE * v;
                acc += v * atts[c];
            }
            e[i] = acc;
            bk[k] = d >> 7;
            pk[k] = (unsigned)(d & 127);
            ev[k] = acc;
            atomicAdd(&cnts[bk[k]], 1);
        }
    }
    __syncthreads();
    for (int b = t; b < NBK; b += 256)
        if (cnts[b] > 0) gbase[b] = atomicAdd(&gcur[b], cnts[b]);
    __syncthreads();
#pragma unroll
    for (int k = 0; k < 16; k++) {
        if (bk[k] >= 0) {
            const int slot = gbase[bk[k]] + atomicAdd(&lfill[bk[k]], 1);
            tmp[(size_t)bk[k] * BCAP + slot] = make_uint2(pk[k], __float_as_uint(ev[k]));
        }
    }
}

// ---------- FAST: per-bucket layer-2 denominator (1 LDS atomic/rec, ~21us) ---
__global__ void nodeB2_kernel(const uint2* __restrict__ tmp, const int* __restrict__ gcur,
                              float* __restrict__ den2) {
    __shared__ float den[NPB];
    const int t = threadIdx.x;            // 512
    const int b = blockIdx.x;
    const int count = gcur[b];
    const uint2* rec = tmp + (size_t)b * BCAP;
    for (int i = t; i < NPB; i += 512) den[i] = 0.f;
    __syncthreads();
    for (int j = t; j < count; j += 512) {
        const uint2 r = rec[j];
        atomicAdd(&den[r.x & 127u], __expf(__uint_as_float(r.y)));
    }
    __syncthreads();
    const int n0 = b * NPB;
    for (int i = t; i < NPB; i += 512) {
        const int node = n0 + i;
        if (node < NN) den2[node] = den[i];
    }
}

// ---------- FAST: alpha2 = exp(e2)/den2[dst] -> [2E,3E) ----------
__global__ void final2_kernel(const int* __restrict__ dst,
                              const float* __restrict__ e,
                              const float* __restrict__ den2,
                              float* __restrict__ out) {
    const int i = blockIdx.x * 256 + threadIdx.x;
    const int d = dst[i];
    out[2 * EE + i] = __expf(e[i]) / (den2[d] + 1e-16f);
}

// ---------- edges passthrough -> floats [0,2E), LAST ----------
__global__ void edges_kernel(const int* __restrict__ edges, float* __restrict__ out) {
    const int i = blockIdx.x * 256 + threadIdx.x;   // grid covers 2E
    out[i] = (float)edges[i];
}

// ================= FALLBACK PATH (round-5/6, known-good) =================
__global__ void edge1f_kernel(const int* __restrict__ edges,
                              const float* __restrict__ ew,
                              const bf16* __restrict__ xl1, const bf16* __restrict__ xr1,
                              const float* __restrict__ We1, const float* __restrict__ att1,
                              float* __restrict__ e1, int* __restrict__ cnt,
                              unsigned* __restrict__ m1enc) {
    __shared__ float Wes[CC1], atts[CC1];
    if (threadIdx.x < CC1) {
        Wes[threadIdx.x]  = We1[threadIdx.x];
        atts[threadIdx.x] = att1[threadIdx.x];
    }
    __syncthreads();
    const int e = blockIdx.x * 256 + threadIdx.x;
    const int s = edges[e], d = edges[EE + e];
    const float w = ew[e];
    float a[CC1], b[CC1];
    ld8bf(xl1 + s * CC1, a); ld8bf(xl1 + s * CC1 + 8, a + 8);
    ld8bf(xr1 + d * CC1, b); ld8bf(xr1 + d * CC1 + 8, b + 8);
    float acc = 0.f;
#pragma unroll
    for (int c = 0; c < CC1; c++) {
        float v = a[c] + b[c] + w * Wes[c];
        v = v > 0.f ? v : NEG_SLOPE * v;
        acc += v * atts[c];
    }
    e1[e] = acc;
    atomicAdd(&cnt[d], 1);
    atomicMax(&m1enc[d], enc_f(acc));
}

__global__ void scan_kernel(const int* __restrict__ cnt, int* __restrict__ off) {
    __shared__ int part[1024];
    const int t = threadIdx.x;
    const int chunk = (NN + 1023) / 1024;
    const int beg = t * chunk;
    const int end = min(beg + chunk, NN);
    int s = 0;
    for (int i = beg; i < end; i++) s += cnt[i];
    part[t] = s;
    __syncthreads();
    for (int o = 1; o < 1024; o <<= 1) {
        int v = (t >= o) ? part[t - o] : 0;
        __syncthreads();
        part[t] += v;
        __syncthreads();
    }
    int run = (t > 0) ? part[t - 1] : 0;
    for (int i = beg; i < end; i++) { off[i] = run; run += cnt[i]; }
    if (t == 1023) off[NN] = part[1023];
}

__global__ void scatter_kernel(const int* __restrict__ edges,
                               const int* __restrict__ off, int* __restrict__ cnt,
                               int* __restrict__ csr) {
    const int i = blockIdx.x * 256 + threadIdx.x;
    const int d = edges[EE + i];
    const int r = atomicSub(&cnt[d], 1);
    csr[off[d] + r - 1] = i;
}

__global__ void node1s_kernel(const int* __restrict__ off, const int* __restrict__ csr,
                              const int* __restrict__ edges,
                              const float* __restrict__ e1, const bf16* __restrict__ xl1,
                              float* __restrict__ den1, bf16* __restrict__ out1) {
    const int t = blockIdx.x * 256 + threadIdx.x;
    const int n = t >> 4, c = t & 15;
    const int beg = off[n], end = off[n + 1];
    float m = -3.0e38f, l = 0.f, acc = 0.f;
    for (int j = beg; j < end; j++) {
        const int eid = csr[j];
        const float s = e1[eid];
        const int src = edges[eid];
        const float xv = b2f(xl1[src * CC1 + c]);
        if (s > m) { const float r = __expf(m - s); l *= r; acc *= r; m = s; }
        const float p = __expf(s - m);
        l += p; acc += p * xv;
    }
    out1[n * CC1 + c] = __float2bfloat16(l > 0.f ? acc / l : 0.f);
    if (c == 0) den1[n] = l;
}

__global__ void edge2enc_kernel(const int* __restrict__ edges,
                                float* __restrict__ e,
                                const unsigned* __restrict__ m1enc,
                                const float* __restrict__ den1,
                                const bf16* __restrict__ xl2, const bf16* __restrict__ xr2,
                                const float* __restrict__ We2, const float* __restrict__ att2) {
    __shared__ float Wes[CC2], atts[CC2];
    if (threadIdx.x < CC2) {
        Wes[threadIdx.x]  = We2[threadIdx.x];
        atts[threadIdx.x] = att2[threadIdx.x];
    }
    __syncthreads();
    const int i = blockIdx.x * 256 + threadIdx.x;
    const int s = edges[i], d = edges[EE + i];
    const float w = __expf(e[i] - dec_f(m1enc[d])) / (den1[d] + 1e-16f);
    float a[CC2], b[CC2];
#pragma unroll
    for (int q = 0; q < 4; q++) {
        ld8bf(xl2 + s * CC2 + 8 * q, a + 8 * q);
        ld8bf(xr2 + d * CC2 + 8 * q, b + 8 * q);
    }
    float acc = 0.f;
#pragma unroll
    for (int c = 0; c < CC2; c++) {
        float v = a[c] + b[c] + w * Wes[c];
        v = v > 0.f ? v : NEG_SLOPE * v;
        acc += v * atts[c];
    }
    e[i] = acc;
}

__global__ void max2_kernel(const int* __restrict__ dst, const float* __restrict__ e2,
                            unsigned* __restrict__ m2) {
    const int i = blockIdx.x * 256 + threadIdx.x;
    atomicMax(&m2[dst[i]], enc_f(e2[i]));
}

__global__ void num2_kernel(const int* __restrict__ dst,
                            const unsigned* __restrict__ m2,
                            float* __restrict__ e, float* __restrict__ den2) {
    const int i = blockIdx.x * 256 + threadIdx.x;
    const int d = dst[i];
    const float v = __expf(e[i] - dec_f(m2[d]));
    e[i] = v;
    atomicAdd(&den2[d], v);
}

__global__ void finalold_kernel(const int* __restrict__ dst,
                                const float* __restrict__ e,
                                const float* __restrict__ den2,
                                float* __restrict__ out) {
    const int i = blockIdx.x * 256 + threadIdx.x;
    const int d = dst[i];
    out[2 * EE + i] = e[i] / (den2[d] + 1e-16f);
}

extern "C" void kernel_launch(void* const* d_in, const int* in_sizes, int n_in,
                              void* d_out, int out_size, void* d_ws, size_t ws_size,
                              hipStream_t stream) {
    const float* x    = (const float*)d_in[0];
    const int*  edges = (const int*)d_in[1];
    const float* ew   = (const float*)d_in[2];
    const float* Wl1  = (const float*)d_in[3];
    const float* bl1  = (const float*)d_in[4];
    const float* Wr1  = (const float*)d_in[5];
    const float* br1  = (const float*)d_in[6];
    const float* We1  = (const float*)d_in[7];
    const float* att1 = (const float*)d_in[8];
    const float* b1   = (const float*)d_in[9];
    const float* Wl2  = (const float*)d_in[10];
    const float* bl2  = (const float*)d_in[11];
    const float* Wr2  = (const float*)d_in[12];
    const float* br2  = (const float*)d_in[13];
    const float* We2  = (const float*)d_in[14];
    const float* att2 = (const float*)d_in[15];
    float* out = (float*)d_out;

    const int* dst = edges + EE;
    const int EG = EE / 256;                          // 12500

    // ---- Workspace: tmp(32MB) | gcur | bbase | csr2(25.6MB) | off(400KB) ----
    const size_t dpBytes = (size_t)NBK * BCAP * 8;
    uint2* tmp   = (uint2*)d_ws;
    int*   gcur  = (int*)((char*)d_ws + dpBytes);
    int*   bbase = (int*)((char*)d_ws + dpBytes + 4096);
    uint2* csr2  = (uint2*)((char*)d_ws + dpBytes + 8192);
    int*   off   = (int*)((char*)d_ws + dpBytes + 8192 + (size_t)EE * 8);
    const size_t ws_need = dpBytes + 8192 + (size_t)EE * 8
                         + (size_t)(NN + 4) * 4;      // ~58MB (proven ws>=160MB)
    const bool fast = (d_ws != nullptr) && (ws_size >= ws_need);

    if (fast) {
        // ---- fast layout ----
        float* e = out;                               // [0,E)
        bf16*  xl2  = (bf16*)(out + EE);              // R: N*32 bf16
        bf16*  xr2  = xl2 + NN * CC2;                 // R: N*32 bf16
        float* den2 = out + EE;                       // R base (xl2/xr2 dead)
        float* den1 = out + 2 * EE;                   // C region
        bf16*  xl1  = (bf16*)(den1 + NN);             // 16B-aligned
        bf16*  xr1  = xl1 + NN * CC1;
        bf16*  out1 = xr1 + NN * CC1;

        hipMemsetAsync(gcur, 0, (size_t)NBK * sizeof(int), stream);
        lin1_kernel    <<<NN / 8, 256, 0, stream>>>(x, Wl1, bl1, Wr1, br1, xl1, xr1);
        edge1bin_kernel<<<ABLK, 256, 0, stream>>>(edges, ew, xl1, xr1, We1, att1,
                                                  e, tmp, gcur);
        scanB_kernel   <<<1, 1024, 0, stream>>>(gcur, bbase, off);
        binB2_kernel   <<<NBK, 512, 0, stream>>>(tmp, gcur, bbase, csr2, off);
        node1f_kernel  <<<NN * 16 / 256, 256, 0, stream>>>(off, csr2, xl1, den1, out1);
        lin2_kernel    <<<NN / 4, 256, 0, stream>>>(out1, b1, Wl2, bl2, Wr2, br2, xl2, xr2);
        hipMemsetAsync(gcur, 0, (size_t)NBK * sizeof(int), stream);
        edge2bin_kernel<<<ABLK, 256, 0, stream>>>(edges, e, den1, xl2, xr2,
                                                  We2, att2, tmp, gcur);
        // xl2/xr2 dead: den2 overlays R base
        nodeB2_kernel  <<<NBK, 512, 0, stream>>>(tmp, gcur, den2);
        final2_kernel  <<<EG, 256, 0, stream>>>(dst, e, den2, out);
        edges_kernel   <<<2 * EG, 256, 0, stream>>>(edges, out);
    } else {
        // ---- fallback layout (round-6) ----
        float*    e    = out;
        int*      csr  = (int*)(out + EE);
        bf16*     xl2  = (bf16*)(out + EE);
        bf16*     xr2  = xl2 + NN * CC2;
        unsigned* m2   = (unsigned*)(out + EE);
        float*    den2 = (float*)(out + EE) + NN;
        int*      offF  = (int*)(out + 2 * EE);
        unsigned* m1enc = (unsigned*)(offF + NN + 4);
        int*      cnt   = (int*)(m1enc + NN);
        float*    den1  = (float*)(cnt + NN);
        bf16*     xl1   = (bf16*)(den1 + NN);
        bf16*     xr1   = xl1 + NN * CC1;
        bf16*     out1  = xr1 + NN * CC1;

        hipMemsetAsync(m1enc, 0, (size_t)2 * NN * sizeof(int), stream);  // m1enc+cnt
        lin1_kernel   <<<NN / 8, 256, 0, stream>>>(x, Wl1, bl1, Wr1, br1, xl1, xr1);
        edge1f_kernel <<<EG, 256, 0, stream>>>(edges, ew, xl1, xr1, We1, att1,
                                               e, cnt, m1enc);
        scan_kernel   <<<1, 1024, 0, stream>>>(cnt, offF);
        scatter_kernel<<<EG, 256, 0, stream>>>(edges, offF, cnt, csr);
        node1s_kernel <<<NN * 16 / 256, 256, 0, stream>>>(offF, csr, edges, e, xl1,
                                                          den1, out1);
        lin2_kernel   <<<NN / 4, 256, 0, stream>>>(out1, b1, Wl2, bl2, Wr2, br2, xl2, xr2);
        edge2enc_kernel<<<EG, 256, 0, stream>>>(edges, e, m1enc, den1, xl2, xr2,
                                                We2, att2);
        hipMemsetAsync(m2, 0, (size_t)2 * NN * sizeof(float), stream);
        max2_kernel   <<<EG, 256, 0, stream>>>(dst, e, m2);
        num2_kernel   <<<EG, 256, 0, stream>>>(dst, m2, e, den2);
        finalold_kernel<<<EG, 256, 0, stream>>>(dst, e, den2, out);
        edges_kernel  <<<2 * EG, 256, 0, stream>>>(edges, out);
    }
}

// Round 8
// 547.753 us; speedup vs baseline: 1.7726x; 1.0881x over previous
//
#include <hip/hip_runtime.h>
#include <hip/hip_bf16.h>

// GATv2 x2 on MI355X. N=100000, E=3200000, D=128, H=1, C1=16, C2=32.
// Inputs f32; d_out f32, 3E floats = [edges(2E) | alpha2(E)].
// Round-14: edge2bin is #1 (141us, 3.0TB/s = 47% of achievable, occupancy 24%).
// Concurrency cap identified: 16 edges/thread x 256 thr => 3125 waves total =
// 12 waves/CU grid ceiling. Fix (a): 512 thr x 8 edges/thread, same ACH=4096
// (bucket-run length preserved -> no extra write amp), 2x waves.
// Fix (b): fuse {scanB, binB2, node1f} -> bucket1_kernel: records sorted into
// a 40KB LDS buffer (hist+countdown, 2 LDS atomics/rec), then per-node 16-lane
// register-FMA aggregation straight from LDS. Kills the 51MB csr2 round-trip.
//
// d_out layout:
//  A [0,E):    e      score1 -> score2 (slot-in-place)
//  R [E,2E):   xl2/xr2 (N*64 bf16 = E floats) -> den2(N f32) at R base
//  C [2E,3E):  den1(N) xl1(8N) xr1(8N) out1(8N) = 2.5M floats
//  edges passthrough overwrites [0,2E) LAST.
// d_ws (32MB; proven >=160MB): tmp uint2[782*5120] | gcur[782]

#define NN 100000
#define EE 3200000
#define DD 128
#define CC1 16
#define CC2 32
#define NEG_SLOPE 0.2f

#define NPB  128                        // nodes per bucket
#define NBK  782                        // ceil(NN/NPB); 782*128 = 100096
#define BCAP 5120                       // records/bucket (mean 4092, +16 sigma)
#define ACH  4096                       // edges per edge*bin block (8/thread @512)
#define ABLK 782                        // ceil(EE/ACH)

typedef __hip_bfloat16 bf16;

__device__ __forceinline__ float b2f(bf16 v) { return __bfloat162float(v); }

// load 8 consecutive bf16 -> 8 floats (one 16B load); bases verified 16B-aligned
__device__ __forceinline__ void ld8bf(const bf16* p, float* f) {
    uint4 u = *(const uint4*)p;
    const unsigned w[4] = {u.x, u.y, u.z, u.w};
#pragma unroll
    for (int i = 0; i < 4; i++) {
        f[2 * i]     = __uint_as_float(w[i] << 16);
        f[2 * i + 1] = __uint_as_float(w[i] & 0xffff0000u);
    }
}

// Order-preserving float<->uint encode for atomicMax (fallback path only).
__device__ __forceinline__ unsigned enc_f(float x) {
    unsigned b = __float_as_uint(x);
    return (b & 0x80000000u) ? ~b : (b | 0x80000000u);
}
__device__ __forceinline__ float dec_f(unsigned u) {
    unsigned b = (u & 0x80000000u) ? (u & 0x7fffffffu) : ~u;
    return __uint_as_float(b);
}

// ---------- Layer-1 node transform: xl1/xr1 = x@W + b (bf16 out) ----------
__global__ void lin1_kernel(const float* __restrict__ x,
                            const float* __restrict__ Wl, const float* __restrict__ bl,
                            const float* __restrict__ Wr, const float* __restrict__ br,
                            bf16* __restrict__ xl1, bf16* __restrict__ xr1) {
    __shared__ float Ws[DD][32];   // col<16: Wl, col>=16: Wr
    __shared__ float xs[8][DD];
    const int t = threadIdx.x;
    for (int i = t; i < DD * CC1; i += 256) {
        int k = i >> 4, c = i & 15;
        Ws[k][c]      = Wl[i];
        Ws[k][c + 16] = Wr[i];
    }
    const int node0 = blockIdx.x * 8;
    for (int i = t; i < 8 * DD; i += 256) {
        int n = i >> 7, k = i & 127;
        xs[n][k] = x[(node0 + n) * DD + k];
    }
    __syncthreads();
    const int n = t >> 5, c = t & 31;
    const int node = node0 + n;
    float acc = 0.f;
#pragma unroll 16
    for (int k = 0; k < DD; k++) acc += xs[n][k] * Ws[k][c];
    if (c < 16) xl1[node * CC1 + c]        = __float2bfloat16(acc + bl[c]);
    else        xr1[node * CC1 + (c - 16)] = __float2bfloat16(acc + br[c - 16]);
}

// ---------- FAST: Layer-1 edge scores fused with bucket binning ----------
// 512 threads x 8 edges; record = ( d&127 | src<<7 , e1 ); no global atomics.
__global__ void edge1bin_kernel(const int* __restrict__ edges,
                                const float* __restrict__ ew,
                                const bf16* __restrict__ xl1, const bf16* __restrict__ xr1,
                                const float* __restrict__ We1, const float* __restrict__ att1,
                                float* __restrict__ e1,
                                uint2* __restrict__ tmp, int* __restrict__ gcur) {
    __shared__ float Wes[CC1], atts[CC1];
    __shared__ int cnts[NBK], gbase[NBK], lfill[NBK];
    const int t = threadIdx.x;    // 512
    if (t < CC1) { Wes[t] = We1[t]; atts[t] = att1[t]; }
    for (int b = t; b < NBK; b += 512) { cnts[b] = 0; lfill[b] = 0; }
    __syncthreads();
    const int base = blockIdx.x * ACH;
    unsigned pk[8]; float ev[8]; int bk[8];
#pragma unroll
    for (int k = 0; k < 8; k++) {
        const int i = base + k * 512 + t;
        bk[k] = -1;
        if (i < EE) {
            const int s = edges[i], d = edges[EE + i];
            const float w = ew[i];
            float a[CC1], b[CC1];
            ld8bf(xl1 + s * CC1, a); ld8bf(xl1 + s * CC1 + 8, a + 8);
            ld8bf(xr1 + d * CC1, b); ld8bf(xr1 + d * CC1 + 8, b + 8);
            float acc = 0.f;
#pragma unroll
            for (int c = 0; c < CC1; c++) {
                float v = a[c] + b[c] + w * Wes[c];
                v = v > 0.f ? v : NEG_SLOPE * v;
                acc += v * atts[c];
            }
            e1[i] = acc;
            bk[k] = d >> 7;
            pk[k] = (unsigned)(d & 127) | ((unsigned)s << 7);
            ev[k] = acc;
            atomicAdd(&cnts[bk[k]], 1);
        }
    }
    __syncthreads();
    for (int b = t; b < NBK; b += 512)
        if (cnts[b] > 0) gbase[b] = atomicAdd(&gcur[b], cnts[b]);
    __syncthreads();
#pragma unroll
    for (int k = 0; k < 8; k++) {
        if (bk[k] >= 0) {
            const int slot = gbase[bk[k]] + atomicAdd(&lfill[bk[k]], 1);
            tmp[(size_t)bk[k] * BCAP + slot] = make_uint2(pk[k], __float_as_uint(ev[k]));
        }
    }
}

// ---------- FAST: fused bucket sort + per-node register aggregation ----------
// Pass1 hist (1 LDS atomic/rec) -> t0 scan -> pass2 sort into 40KB LDS
// (1 LDS atomic + 1 LDS write/rec; tmp re-read is L2-hot) -> pass3 per-node
// 16-lane-group register FMA from LDS (zero LDS atomics, R7-proven shape).
__global__ void bucket1_kernel(const uint2* __restrict__ tmp, const int* __restrict__ gcur,
                               const bf16* __restrict__ xl1,
                               float* __restrict__ den1, bf16* __restrict__ out1) {
    __shared__ int cnt[NPB];          // hist, then countdown cursor
    __shared__ int loff[NPB + 1];     // local exclusive prefix
    __shared__ uint2 srt[BCAP];       // 40KB sorted (src, p=exp(e))
    const int t = threadIdx.x;        // 512
    const int b = blockIdx.x;
    const int count = gcur[b];
    const uint2* rec = tmp + (size_t)b * BCAP;
    for (int i = t; i < NPB; i += 512) cnt[i] = 0;
    __syncthreads();
    for (int j = t; j < count; j += 512) atomicAdd(&cnt[rec[j].x & 127u], 1);
    __syncthreads();
    if (t == 0) {
        int run = 0;
#pragma unroll
        for (int i = 0; i < NPB; i++) { loff[i] = run; run += cnt[i]; }
        loff[NPB] = run;
    }
    __syncthreads();
    for (int j = t; j < count; j += 512) {
        const uint2 r = rec[j];       // second read: L2-hot (40KB window)
        const int d = (int)(r.x & 127u);
        const int rr = atomicSub(&cnt[d], 1);           // rr in [1..deg]
        srt[loff[d] + rr - 1] =
            make_uint2(r.x >> 7, __float_as_uint(__expf(__uint_as_float(r.y))));
    }
    __syncthreads();
    const int g = t >> 4, c = t & 15; // 32 groups x 16 channel-lanes
    const int n0 = b * NPB;
    for (int dn = g; dn < NPB; dn += 32) {
        const int node = n0 + dn;
        if (node >= NN) continue;     // uniform within group
        const int beg = loff[dn], end = loff[dn + 1];
        float l = 0.f, acc = 0.f;
        for (int j = beg; j < end; j++) {
            const uint2 r = srt[j];               // broadcast across 16 lanes
            const float p = __uint_as_float(r.y);
            acc += p * b2f(xl1[r.x * CC1 + c]);   // one 64B line per record
            l += p;
        }
        out1[node * CC1 + c] = __float2bfloat16(l > 0.f ? acc / l : 0.f);
        if (c == 0) den1[node] = l;
    }
}

// ---------- Layer-2 node transform: h = relu(out1+b1); xl2/xr2 = h@W2 (bf16) ----------
__global__ void lin2_kernel(const bf16* __restrict__ out1, const float* __restrict__ b1,
                            const float* __restrict__ Wl2, const float* __restrict__ bl2,
                            const float* __restrict__ Wr2, const float* __restrict__ br2,
                            bf16* __restrict__ xl2, bf16* __restrict__ xr2) {
    __shared__ float Ws[CC1][64];  // col<32: Wl2, col>=32: Wr2
    __shared__ float hs[4][CC1];
    const int t = threadIdx.x;
    for (int i = t; i < CC1 * CC2; i += 256) {
        int k = i >> 5, c = i & 31;
        Ws[k][c]      = Wl2[i];
        Ws[k][c + 32] = Wr2[i];
    }
    const int node0 = blockIdx.x * 4;
    if (t < 64) {
        int n = t >> 4, k = t & 15;
        float v = b2f(out1[(node0 + n) * CC1 + k]) + b1[k];
        hs[n][k] = v > 0.f ? v : 0.f;
    }
    __syncthreads();
    const int n = t >> 6, c = t & 63;
    const int node = node0 + n;
    float acc = 0.f;
#pragma unroll
    for (int k = 0; k < CC1; k++) acc += hs[n][k] * Ws[k][c];
    if (c < 32) xl2[node * CC2 + c]        = __float2bfloat16(acc + bl2[c]);
    else        xr2[node * CC2 + (c - 32)] = __float2bfloat16(acc + br2[c - 32]);
}

// ---------- FAST: Layer-2 edge scores fused with bucket binning ----------
// 512 threads x 8 edges; alpha1 = exp(e1)/den1 inline; record = ( d&127 , e2 ).
__global__ void edge2bin_kernel(const int* __restrict__ edges,
                                float* __restrict__ e,     // in: score1, out: score2
                                const float* __restrict__ den1,
                                const bf16* __restrict__ xl2, const bf16* __restrict__ xr2,
                                const float* __restrict__ We2, const float* __restrict__ att2,
                                uint2* __restrict__ tmp, int* __restrict__ gcur) {
    __shared__ float Wes[CC2], atts[CC2];
    __shared__ int cnts[NBK], gbase[NBK], lfill[NBK];
    const int t = threadIdx.x;    // 512
    if (t < CC2) { Wes[t] = We2[t]; atts[t] = att2[t]; }
    for (int b = t; b < NBK; b += 512) { cnts[b] = 0; lfill[b] = 0; }
    __syncthreads();
    const int base = blockIdx.x * ACH;
    unsigned pk[8]; float ev[8]; int bk[8];
#pragma unroll
    for (int k = 0; k < 8; k++) {
        const int i = base + k * 512 + t;
        bk[k] = -1;
        if (i < EE) {
            const int s = edges[i], d = edges[EE + i];
            const float w = __expf(e[i]) / (den1[d] + 1e-16f);  // alpha1, no shift
            float a[CC2], b[CC2];
#pragma unroll
            for (int q = 0; q < 4; q++) {
                ld8bf(xl2 + s * CC2 + 8 * q, a + 8 * q);
                ld8bf(xr2 + d * CC2 + 8 * q, b + 8 * q);
            }
            float acc = 0.f;
#pragma unroll
            for (int c = 0; c < CC2; c++) {
                float v = a[c] + b[c] + w * Wes[c];
                v = v > 0.f ? v : NEG_SLOPE * v;
                acc += v * atts[c];
            }
            e[i] = acc;
            bk[k] = d >> 7;
            pk[k] = (unsigned)(d & 127);
            ev[k] = acc;
            atomicAdd(&cnts[bk[k]], 1);
        }
    }
    __syncthreads();
    for (int b = t; b < NBK; b += 512)
        if (cnts[b] > 0) gbase[b] = atomicAdd(&gcur[b], cnts[b]);
    __syncthreads();
#pragma unroll
    for (int k = 0; k < 8; k++) {
        if (bk[k] >= 0) {
            const int slot = gbase[bk[k]] + atomicAdd(&lfill[bk[k]], 1);
            tmp[(size_t)bk[k] * BCAP + slot] = make_uint2(pk[k], __float_as_uint(ev[k]));
        }
    }
}

// ---------- FAST: per-bucket layer-2 denominator (1 LDS atomic/rec) ----------
__global__ void nodeB2_kernel(const uint2* __restrict__ tmp, const int* __restrict__ gcur,
                              float* __restrict__ den2) {
    __shared__ float den[NPB];
    const int t = threadIdx.x;            // 512
    const int b = blockIdx.x;
    const int count = gcur[b];
    const uint2* rec = tmp + (size_t)b * BCAP;
    for (int i = t; i < NPB; i += 512) den[i] = 0.f;
    __syncthreads();
    for (int j = t; j < count; j += 512) {
        const uint2 r = rec[j];
        atomicAdd(&den[r.x & 127u], __expf(__uint_as_float(r.y)));
    }
    __syncthreads();
    const int n0 = b * NPB;
    for (int i = t; i < NPB; i += 512) {
        const int node = n0 + i;
        if (node < NN) den2[node] = den[i];
    }
}

// ---------- FAST: alpha2 = exp(e2)/den2[dst] -> [2E,3E) ----------
__global__ void final2_kernel(const int* __restrict__ dst,
                              const float* __restrict__ e,
                              const float* __restrict__ den2,
                              float* __restrict__ out) {
    const int i = blockIdx.x * 256 + threadIdx.x;
    const int d = dst[i];
    out[2 * EE + i] = __expf(e[i]) / (den2[d] + 1e-16f);
}

// ---------- edges passthrough -> floats [0,2E), LAST ----------
__global__ void edges_kernel(const int* __restrict__ edges, float* __restrict__ out) {
    const int i = blockIdx.x * 256 + threadIdx.x;   // grid covers 2E
    out[i] = (float)edges[i];
}

// ================= FALLBACK PATH (round-5/6, known-good) =================
__global__ void edge1f_kernel(const int* __restrict__ edges,
                              const float* __restrict__ ew,
                              const bf16* __restrict__ xl1, const bf16* __restrict__ xr1,
                              const float* __restrict__ We1, const float* __restrict__ att1,
                              float* __restrict__ e1, int* __restrict__ cnt,
                              unsigned* __restrict__ m1enc) {
    __shared__ float Wes[CC1], atts[CC1];
    if (threadIdx.x < CC1) {
        Wes[threadIdx.x]  = We1[threadIdx.x];
        atts[threadIdx.x] = att1[threadIdx.x];
    }
    __syncthreads();
    const int e = blockIdx.x * 256 + threadIdx.x;
    const int s = edges[e], d = edges[EE + e];
    const float w = ew[e];
    float a[CC1], b[CC1];
    ld8bf(xl1 + s * CC1, a); ld8bf(xl1 + s * CC1 + 8, a + 8);
    ld8bf(xr1 + d * CC1, b); ld8bf(xr1 + d * CC1 + 8, b + 8);
    float acc = 0.f;
#pragma unroll
    for (int c = 0; c < CC1; c++) {
        float v = a[c] + b[c] + w * Wes[c];
        v = v > 0.f ? v : NEG_SLOPE * v;
        acc += v * atts[c];
    }
    e1[e] = acc;
    atomicAdd(&cnt[d], 1);
    atomicMax(&m1enc[d], enc_f(acc));
}

__global__ void scan_kernel(const int* __restrict__ cnt, int* __restrict__ off) {
    __shared__ int part[1024];
    const int t = threadIdx.x;
    const int chunk = (NN + 1023) / 1024;
    const int beg = t * chunk;
    const int end = min(beg + chunk, NN);
    int s = 0;
    for (int i = beg; i < end; i++) s += cnt[i];
    part[t] = s;
    __syncthreads();
    for (int o = 1; o < 1024; o <<= 1) {
        int v = (t >= o) ? part[t - o] : 0;
        __syncthreads();
        part[t] += v;
        __syncthreads();
    }
    int run = (t > 0) ? part[t - 1] : 0;
    for (int i = beg; i < end; i++) { off[i] = run; run += cnt[i]; }
    if (t == 1023) off[NN] = part[1023];
}

__global__ void scatter_kernel(const int* __restrict__ edges,
                               const int* __restrict__ off, int* __restrict__ cnt,
                               int* __restrict__ csr) {
    const int i = blockIdx.x * 256 + threadIdx.x;
    const int d = edges[EE + i];
    const int r = atomicSub(&cnt[d], 1);
    csr[off[d] + r - 1] = i;
}

__global__ void node1s_kernel(const int* __restrict__ off, const int* __restrict__ csr,
                              const int* __restrict__ edges,
                              const float* __restrict__ e1, const bf16* __restrict__ xl1,
                              float* __restrict__ den1, bf16* __restrict__ out1) {
    const int t = blockIdx.x * 256 + threadIdx.x;
    const int n = t >> 4, c = t & 15;
    const int beg = off[n], end = off[n + 1];
    float m = -3.0e38f, l = 0.f, acc = 0.f;
    for (int j = beg; j < end; j++) {
        const int eid = csr[j];
        const float s = e1[eid];
        const int src = edges[eid];
        const float xv = b2f(xl1[src * CC1 + c]);
        if (s > m) { const float r = __expf(m - s); l *= r; acc *= r; m = s; }
        const float p = __expf(s - m);
        l += p; acc += p * xv;
    }
    out1[n * CC1 + c] = __float2bfloat16(l > 0.f ? acc / l : 0.f);
    if (c == 0) den1[n] = l;
}

__global__ void edge2enc_kernel(const int* __restrict__ edges,
                                float* __restrict__ e,
                                const unsigned* __restrict__ m1enc,
                                const float* __restrict__ den1,
                                const bf16* __restrict__ xl2, const bf16* __restrict__ xr2,
                                const float* __restrict__ We2, const float* __restrict__ att2) {
    __shared__ float Wes[CC2], atts[CC2];
    if (threadIdx.x < CC2) {
        Wes[threadIdx.x]  = We2[threadIdx.x];
        atts[threadIdx.x] = att2[threadIdx.x];
    }
    __syncthreads();
    const int i = blockIdx.x * 256 + threadIdx.x;
    const int s = edges[i], d = edges[EE + i];
    const float w = __expf(e[i] - dec_f(m1enc[d])) / (den1[d] + 1e-16f);
    float a[CC2], b[CC2];
#pragma unroll
    for (int q = 0; q < 4; q++) {
        ld8bf(xl2 + s * CC2 + 8 * q, a + 8 * q);
        ld8bf(xr2 + d * CC2 + 8 * q, b + 8 * q);
    }
    float acc = 0.f;
#pragma unroll
    for (int c = 0; c < CC2; c++) {
        float v = a[c] + b[c] + w * Wes[c];
        v = v > 0.f ? v : NEG_SLOPE * v;
        acc += v * atts[c];
    }
    e[i] = acc;
}

__global__ void max2_kernel(const int* __restrict__ dst, const float* __restrict__ e2,
                            unsigned* __restrict__ m2) {
    const int i = blockIdx.x * 256 + threadIdx.x;
    atomicMax(&m2[dst[i]], enc_f(e2[i]));
}

__global__ void num2_kernel(const int* __restrict__ dst,
                            const unsigned* __restrict__ m2,
                            float* __restrict__ e, float* __restrict__ den2) {
    const int i = blockIdx.x * 256 + threadIdx.x;
    const int d = dst[i];
    const float v = __expf(e[i] - dec_f(m2[d]));
    e[i] = v;
    atomicAdd(&den2[d], v);
}

__global__ void finalold_kernel(const int* __restrict__ dst,
                                const float* __restrict__ e,
                                const float* __restrict__ den2,
                                float* __restrict__ out) {
    const int i = blockIdx.x * 256 + threadIdx.x;
    const int d = dst[i];
    out[2 * EE + i] = e[i] / (den2[d] + 1e-16f);
}

extern "C" void kernel_launch(void* const* d_in, const int* in_sizes, int n_in,
                              void* d_out, int out_size, void* d_ws, size_t ws_size,
                              hipStream_t stream) {
    const float* x    = (const float*)d_in[0];
    const int*  edges = (const int*)d_in[1];
    const float* ew   = (const float*)d_in[2];
    const float* Wl1  = (const float*)d_in[3];
    const float* bl1  = (const float*)d_in[4];
    const float* Wr1  = (const float*)d_in[5];
    const float* br1  = (const float*)d_in[6];
    const float* We1  = (const float*)d_in[7];
    const float* att1 = (const float*)d_in[8];
    const float* b1   = (const float*)d_in[9];
    const float* Wl2  = (const float*)d_in[10];
    const float* bl2  = (const float*)d_in[11];
    const float* Wr2  = (const float*)d_in[12];
    const float* br2  = (const float*)d_in[13];
    const float* We2  = (const float*)d_in[14];
    const float* att2 = (const float*)d_in[15];
    float* out = (float*)d_out;

    const int* dst = edges + EE;
    const int EG = EE / 256;                          // 12500

    // ---- Workspace: tmp(32MB) | gcur ----
    const size_t dpBytes = (size_t)NBK * BCAP * 8;
    uint2* tmp  = (uint2*)d_ws;
    int*   gcur = (int*)((char*)d_ws + dpBytes);
    const size_t ws_need = dpBytes + 8192;            // 32MB (proven ws>=160MB)
    const bool fast = (d_ws != nullptr) && (ws_size >= ws_need);

    if (fast) {
        // ---- fast layout ----
        float* e = out;                               // [0,E)
        bf16*  xl2  = (bf16*)(out + EE);              // R: N*32 bf16
        bf16*  xr2  = xl2 + NN * CC2;                 // R: N*32 bf16
        float* den2 = out + EE;                       // R base (xl2/xr2 dead)
        float* den1 = out + 2 * EE;                   // C region
        bf16*  xl1  = (bf16*)(den1 + NN);             // 16B-aligned
        bf16*  xr1  = xl1 + NN * CC1;
        bf16*  out1 = xr1 + NN * CC1;

        hipMemsetAsync(gcur, 0, (size_t)NBK * sizeof(int), stream);
        lin1_kernel    <<<NN / 8, 256, 0, stream>>>(x, Wl1, bl1, Wr1, br1, xl1, xr1);
        edge1bin_kernel<<<ABLK, 512, 0, stream>>>(edges, ew, xl1, xr1, We1, att1,
                                                  e, tmp, gcur);
        bucket1_kernel <<<NBK, 512, 0, stream>>>(tmp, gcur, xl1, den1, out1);
        lin2_kernel    <<<NN / 4, 256, 0, stream>>>(out1, b1, Wl2, bl2, Wr2, br2, xl2, xr2);
        hipMemsetAsync(gcur, 0, (size_t)NBK * sizeof(int), stream);
        edge2bin_kernel<<<ABLK, 512, 0, stream>>>(edges, e, den1, xl2, xr2,
                                                  We2, att2, tmp, gcur);
        // xl2/xr2 dead: den2 overlays R base
        nodeB2_kernel  <<<NBK, 512, 0, stream>>>(tmp, gcur, den2);
        final2_kernel  <<<EG, 256, 0, stream>>>(dst, e, den2, out);
        edges_kernel   <<<2 * EG, 256, 0, stream>>>(edges, out);
    } else {
        // ---- fallback layout (round-6) ----
        float*    e    = out;
        int*      csr  = (int*)(out + EE);
        bf16*     xl2  = (bf16*)(out + EE);
        bf16*     xr2  = xl2 + NN * CC2;
        unsigned* m2   = (unsigned*)(out + EE);
        float*    den2 = (float*)(out + EE) + NN;
        int*      offF  = (int*)(out + 2 * EE);
        unsigned* m1enc = (unsigned*)(offF + NN + 4);
        int*      cnt   = (int*)(m1enc + NN);
        float*    den1  = (float*)(cnt + NN);
        bf16*     xl1   = (bf16*)(den1 + NN);
        bf16*     xr1   = xl1 + NN * CC1;
        bf16*     out1  = xr1 + NN * CC1;

        hipMemsetAsync(m1enc, 0, (size_t)2 * NN * sizeof(int), stream);  // m1enc+cnt
        lin1_kernel   <<<NN / 8, 256, 0, stream>>>(x, Wl1, bl1, Wr1, br1, xl1, xr1);
        edge1f_kernel <<<EG, 256, 0, stream>>>(edges, ew, xl1, xr1, We1, att1,
                                               e, cnt, m1enc);
        scan_kernel   <<<1, 1024, 0, stream>>>(cnt, offF);
        scatter_kernel<<<EG, 256, 0, stream>>>(edges, offF, cnt, csr);
        node1s_kernel <<<NN * 16 / 256, 256, 0, stream>>>(offF, csr, edges, e, xl1,
                                                          den1, out1);
        lin2_kernel   <<<NN / 4, 256, 0, stream>>>(out1, b1, Wl2, bl2, Wr2, br2, xl2, xr2);
        edge2enc_kernel<<<EG, 256, 0, stream>>>(edges, e, m1enc, den1, xl2, xr2,
                                                We2, att2);
        hipMemsetAsync(m2, 0, (size_t)2 * NN * sizeof(float), stream);
        max2_kernel   <<<EG, 256, 0, stream>>>(dst, e, m2);
        num2_kernel   <<<EG, 256, 0, stream>>>(dst, m2, e, den2);
        finalold_kernel<<<EG, 256, 0, stream>>>(dst, e, den2, out);
        edges_kernel  <<<2 * EG, 256, 0, stream>>>(edges, out);
    }
}